// Round 9
// baseline (414.236 us; speedup 1.0000x reference)
//
#include <hip/hip_runtime.h>

#define NN 65536
#define BB 64
#define HH 1024
#define MM 64
#define RR 4

__device__ __forceinline__ float waveReduceSum(float v) {
#pragma unroll
  for (int off = 32; off > 0; off >>= 1) v += __shfl_xor(v, off, 64);
  return v;
}

__device__ __forceinline__ float fastPow(float wt, float p) {
  return __expf(p * __logf(wt));
}

// ---------------------------------------------------------------------------
// K1: fused prep. grid 64 (one block per b), block 256.
// Also zero-inits RS0p/RS1p/GSp (contiguous 37888 floats at zbase).
// ---------------------------------------------------------------------------
__global__ __launch_bounds__(256) void prep_kernel(
    const float* __restrict__ h_t,
    const float* __restrict__ key_w, const float* __restrict__ key_b,
    const float* __restrict__ erase_w, const float* __restrict__ erase_b,
    const float* __restrict__ add_w, const float* __restrict__ add_b,
    const float* __restrict__ beta_w, const float* __restrict__ beta_b,
    const float* __restrict__ gate_w, const float* __restrict__ gate_b,
    const float* __restrict__ shift_w, const float* __restrict__ shift_b,
    const float* __restrict__ gamma_w, const float* __restrict__ gamma_b,
    float* __restrict__ kn, float* __restrict__ e_v, float* __restrict__ a_v,
    float* __restrict__ g, float* __restrict__ gamma_, float* __restrict__ s,
    float* __restrict__ betaGlob, float* __restrict__ zbase)
{
  const int b = blockIdx.x;
  const int t = threadIdx.x;
  for (int i = b * 256 + t; i < 37888; i += 16384) zbase[i] = 0.f;
  __shared__ float h_sh[HH];
  __shared__ float red[3][64][4];
  __shared__ float k_sh[64];
  ((float4*)h_sh)[t] = ((const float4*)(h_t + (size_t)b * HH))[t];
  __syncthreads();
  const int c = t & 63, q = t >> 6;
#pragma unroll
  for (int mat = 0; mat < 3; mat++) {
    const float* __restrict__ Wm = (mat == 0) ? key_w : ((mat == 1) ? erase_w : add_w);
    float d = 0.f;
#pragma unroll 8
    for (int i = 0; i < 256; i++)
      d += h_sh[q * 256 + i] * Wm[(q * 256 + i) * 64 + c];
    red[mat][c][q] = d;
  }
  __syncthreads();
  if (t < 64) {
    const float v = red[0][t][0] + red[0][t][1] + red[0][t][2] + red[0][t][3];
    k_sh[t] = fminf(fmaxf(v + key_b[t], 0.f), 1.f);
  } else if (t < 128) {
    const int c2 = t - 64;
    const float v = red[1][c2][0] + red[1][c2][1] + red[1][c2][2] + red[1][c2][3];
    e_v[b * 64 + c2] = fminf(fmaxf(v + erase_b[c2], 0.f), 1.f);
  } else if (t < 192) {
    const int c2 = t - 128;
    const float v = red[2][c2][0] + red[2][c2][1] + red[2][c2][2] + red[2][c2][3];
    a_v[b * 64 + c2] = fminf(fmaxf(v + add_b[c2], 0.f), 1.f);
  } else {
    const int lane = t - 192;
    float o0 = 0.f, o1 = 0.f, o2 = 0.f, o3 = 0.f, o4 = 0.f, o5 = 0.f;
#pragma unroll 4
    for (int k = 0; k < 16; k++) {
      const int hh = lane + k * 64;
      const float hv = h_sh[hh];
      o0 += hv * beta_w[hh];
      o1 += hv * gate_w[hh];
      o2 += hv * gamma_w[hh];
      o3 += hv * shift_w[hh * 3 + 0];
      o4 += hv * shift_w[hh * 3 + 1];
      o5 += hv * shift_w[hh * 3 + 2];
    }
    o0 = waveReduceSum(o0); o1 = waveReduceSum(o1); o2 = waveReduceSum(o2);
    o3 = waveReduceSum(o3); o4 = waveReduceSum(o4); o5 = waveReduceSum(o5);
    if (lane == 0) {
      betaGlob[b] = fmaxf(o0 + beta_b[0], 0.f);
      g[b]        = fminf(fmaxf(o1 + gate_b[0], 0.f), 1.f);
      gamma_[b]   = 1.0f + fmaxf(o2 + gamma_b[0], 0.f);
      const float l0 = o3 + shift_b[0], l1 = o4 + shift_b[1], l2 = o5 + shift_b[2];
      const float mx = fmaxf(l0, fmaxf(l1, l2));
      const float e0 = __expf(l0 - mx), e1 = __expf(l1 - mx), e2 = __expf(l2 - mx);
      const float inv = 1.f / (e0 + e1 + e2);
      s[b * 3 + 0] = e0 * inv; s[b * 3 + 1] = e1 * inv; s[b * 3 + 2] = e2 * inv;
    }
  }
  __syncthreads();
  if (t < 64) {
    float ss = 0.f;
    for (int j = 0; j < 64; j++) ss += k_sh[j] * k_sh[j];
    kn[b * 64 + t] = k_sh[t] / (sqrtf(ss) + 1e-8f);
  }
}

// ---------------------------------------------------------------------------
// K2 / K5: content addressing, row-read-once layout. grid 1024, block 256.
// NEW: unroll 4 on the b-loop -> 4 independent shfl-reduce chains (the
// 6-step waveReduce is ~200cy of serial cross-lane latency per b otherwise).
// ---------------------------------------------------------------------------
__global__ __launch_bounds__(256) void content_kernel(
    const float* __restrict__ mem, const int* __restrict__ bank,
    const float* __restrict__ kn, const float* __restrict__ beta,
    float* __restrict__ E, float* __restrict__ RSp)
{
  const float* Mrow = mem + (bank ? ((size_t)(*bank) * (size_t)NN * MM) : (size_t)0);
  const int t = threadIdx.x;
  const int lane = t & 63;
  const int n = blockIdx.x * 64 + lane;
  const int b0 = (t >> 6) * 16;

  float4 row[16];
  const float4* rp = (const float4*)(Mrow + (size_t)n * MM);
#pragma unroll
  for (int q = 0; q < 16; q++) row[q] = rp[q];
  float ss = 0.f;
#pragma unroll
  for (int q = 0; q < 16; q++)
    ss += row[q].x * row[q].x + row[q].y * row[q].y + row[q].z * row[q].z + row[q].w * row[q].w;
  const float rinv = 1.0f / (sqrtf(ss) + 1e-8f);

  __shared__ float accs[64];
#pragma unroll 4
  for (int i = 0; i < 16; i++) {
    const int rb = __builtin_amdgcn_readfirstlane(b0 + i);
    const float4* kp = (const float4*)(kn + rb * 64);
    float dot = 0.f;
#pragma unroll
    for (int q = 0; q < 16; q++) {
      const float4 kq = kp[q];
      dot += kq.x * row[q].x + kq.y * row[q].y + kq.z * row[q].z + kq.w * row[q].w;
    }
    const float e = __expf(beta[rb] * dot * rinv);
    E[(size_t)rb * NN + n] = e;
    const float r = waveReduceSum(e);
    if (lane == 0) accs[b0 + i] = r;
  }
  __syncthreads();
  if (t < 64) atomicAdd(&RSp[t * 256 + (blockIdx.x & 15) * 16], accs[t]);
}

// ---------------------------------------------------------------------------
// K3: w_pow producer for the WRITE head, float4-vectorized. grid (64, 64).
// ---------------------------------------------------------------------------
__global__ __launch_bounds__(256) void wpow_kernel(
    const float* __restrict__ E, const float* __restrict__ wprev,
    const float* __restrict__ RSp, const float* __restrict__ g,
    const float* __restrict__ gamma_, const float* __restrict__ s,
    float* __restrict__ W, float* __restrict__ GSp, int slot)
{
  const int b = blockIdx.y;
  const float gb = g[b], gmb = gamma_[b];
  const float s0 = s[b * 3], s1 = s[b * 3 + 1], s2 = s[b * 3 + 2];
  float rs = 0.f;
#pragma unroll
  for (int j = 0; j < 16; j++) rs += RSp[b * 256 + j * 16];
  const float gri = gb / rs;
  const float omg = 1.f - gb;
  const float* Eb = E + (size_t)b * NN;
  const float* wb = wprev + (size_t)b * NN;
  const int t = threadIdx.x;
  const int lane = t & 63;
  const int n0 = blockIdx.x * 1024 + t * 4;
  const float4 e4 = *((const float4*)(Eb + n0));
  const float4 w4 = *((const float4*)(wb + n0));
  const float wg0 = gri * e4.x + omg * w4.x;
  const float wg1 = gri * e4.y + omg * w4.y;
  const float wg2 = gri * e4.z + omg * w4.z;
  const float wg3 = gri * e4.w + omg * w4.w;
  float wgL = __shfl_up(wg3, 1, 64);
  float wgR = __shfl_down(wg0, 1, 64);
  if (lane == 0)  wgL = (n0 > 0) ? (gri * Eb[n0 - 1] + omg * wb[n0 - 1]) : 0.f;
  if (lane == 63) wgR = (n0 + 4 < NN) ? (gri * Eb[n0 + 4] + omg * wb[n0 + 4]) : 0.f;
  float4 wp;
  wp.x = fastPow(s0 * wgL + s1 * wg0 + s2 * wg1, gmb);
  wp.y = fastPow(s0 * wg0 + s1 * wg1 + s2 * wg2, gmb);
  wp.z = fastPow(s0 * wg1 + s1 * wg2 + s2 * wg3, gmb);
  wp.w = fastPow(s0 * wg2 + s1 * wg3 + s2 * wgR, gmb);
  *((float4*)(W + (size_t)b * NN + n0)) = wp;
  const float acc = wp.x + wp.y + wp.z + wp.w;
  __shared__ float wsum[4];
  const float w = waveReduceSum(acc);
  if (lane == 0) wsum[t >> 6] = w;
  __syncthreads();
  if (t == 0)
    atomicAdd(&GSp[slot * 1024 + b * 16], wsum[0] + wsum[1] + wsum[2] + wsum[3]);
}

// ---------------------------------------------------------------------------
// K4: apply write head. grid 1024 (64-n), block 256. Only cw staged in LDS.
// ---------------------------------------------------------------------------
__global__ __launch_bounds__(256) void apply_write_kernel(
    const float* __restrict__ W0, const float* __restrict__ GSp,
    const float* __restrict__ e_v, const float* __restrict__ a_v,
    const float* __restrict__ memory, const int* __restrict__ bank,
    float* __restrict__ m1)
{
  __shared__ float cw[64 * 68];
  const int t = threadIdx.x;
  const int n0 = blockIdx.x * 64;
  float gs = 0.f;
#pragma unroll
  for (int j = 0; j < 64; j++) gs += GSp[j * 16];
  const float invGS = 1.0f / (gs + 1e-5f);
#pragma unroll
  for (int rep = 0; rep < 4; rep++) {
    const int idx = rep * 256 + t;
    const int b = idx >> 4, nc = idx & 15;
    float4 v = *((const float4*)(W0 + (size_t)b * NN + n0 + nc * 4));
    v.x *= invGS; v.y *= invGS; v.z *= invGS; v.w *= invGS;
    *((float4*)&cw[b * 68 + nc * 4]) = v;
  }
  __syncthreads();
  const int nq = t >> 4, mq = t & 15;
  float4 er0 = make_float4(0.f,0.f,0.f,0.f), er1 = er0, er2 = er0, er3 = er0;
  float4 ad0 = er0, ad1 = er0, ad2 = er0, ad3 = er0;
#pragma unroll 4
  for (int b = 0; b < 64; b++) {
    const float4 cwv = *((const float4*)&cw[b * 68 + nq * 4]);
    const float4 evv = ((const float4*)(e_v + b * 64))[mq];
    const float4 avv = ((const float4*)(a_v + b * 64))[mq];
    er0.x += cwv.x * evv.x; er0.y += cwv.x * evv.y; er0.z += cwv.x * evv.z; er0.w += cwv.x * evv.w;
    er1.x += cwv.y * evv.x; er1.y += cwv.y * evv.y; er1.z += cwv.y * evv.z; er1.w += cwv.y * evv.w;
    er2.x += cwv.z * evv.x; er2.y += cwv.z * evv.y; er2.z += cwv.z * evv.z; er2.w += cwv.z * evv.w;
    er3.x += cwv.w * evv.x; er3.y += cwv.w * evv.y; er3.z += cwv.w * evv.z; er3.w += cwv.w * evv.w;
    ad0.x += cwv.x * avv.x; ad0.y += cwv.x * avv.y; ad0.z += cwv.x * avv.z; ad0.w += cwv.x * avv.w;
    ad1.x += cwv.y * avv.x; ad1.y += cwv.y * avv.y; ad1.z += cwv.y * avv.z; ad1.w += cwv.y * avv.w;
    ad2.x += cwv.z * avv.x; ad2.y += cwv.z * avv.y; ad2.z += cwv.z * avv.z; ad2.w += cwv.z * avv.w;
    ad3.x += cwv.w * avv.x; ad3.y += cwv.w * avv.y; ad3.z += cwv.w * avv.z; ad3.w += cwv.w * avv.w;
  }
  const float* M0 = memory + (size_t)(*bank) * (size_t)NN * MM;
#pragma unroll
  for (int i = 0; i < 4; i++) {
    const int n = n0 + nq * 4 + i;
    const float4 mv = ((const float4*)(M0 + (size_t)n * MM))[mq];
    const float4 er = (i == 0) ? er0 : (i == 1) ? er1 : (i == 2) ? er2 : er3;
    const float4 ad = (i == 0) ? ad0 : (i == 1) ? ad1 : (i == 2) ? ad2 : ad3;
    float4 o;
    o.x = mv.x * (1.f - er.x) + ad.x;
    o.y = mv.y * (1.f - er.y) + ad.y;
    o.z = mv.z * (1.f - er.z) + ad.z;
    o.w = mv.w * (1.f - er.w) + ad.w;
    ((float4*)(m1 + (size_t)n * MM))[mq] = o;
  }
}

// ---------------------------------------------------------------------------
// K6: per-r fused wpow+gemm — FROZEN round-3/8 structure (123us, occ 43%,
// VGPR 64). grid (512, 4). Do not trade occupancy for per-thread work:
// keep VGPR <= 64, LDS <= 19.4KB (R1/R4/R5/R7 all regressed).
// ---------------------------------------------------------------------------
__global__ __launch_bounds__(256) void rheads_kernel(
    const float* __restrict__ E, const float* __restrict__ wr,
    const float* __restrict__ m1, const float* __restrict__ RSp,
    const float* __restrict__ g, const float* __restrict__ gamma_,
    const float* __restrict__ s,
    float* __restrict__ part, float* __restrict__ GSp)
{
  __shared__ float g_sh[64], gm_sh[64], ri_sh[64];
  __shared__ float s0_sh[64], s1_sh[64], s2_sh[64];
  __shared__ float w_shT[64 * 68];   // [n_local][b], pad 68
  __shared__ float gsred[4];
  const int sc = blockIdx.x, r = blockIdx.y;
  const int t = threadIdx.x;
  if (t < 64) {
    float rs = 0.f;
#pragma unroll
    for (int j = 0; j < 16; j++) rs += RSp[t * 256 + j * 16];
    ri_sh[t] = 1.0f / rs;
    g_sh[t] = g[t];
    gm_sh[t] = gamma_[t];
    s0_sh[t] = s[t * 3 + 0];
    s1_sh[t] = s[t * 3 + 1];
    s2_sh[t] = s[t * 3 + 2];
  }
  __syncthreads();
  const int n_l = t & 63, bg = t >> 6;
  const int bq = t >> 4, mq = t & 15;
  const float* __restrict__ wrr = wr + (size_t)r * BB * NN;
  float4 acc[4];
#pragma unroll
  for (int j = 0; j < 4; j++) acc[j] = make_float4(0.f, 0.f, 0.f, 0.f);
  float gs_acc = 0.f;

  for (int st = 0; st < 2; st++) {
    if (st) __syncthreads();  // gemm finished reading w_shT
    const int n0 = (sc * 2 + st) * 64;
    const int n = n0 + n_l;
    // ---- produce w tile: wave bg owns b in [bg*16, bg*16+16) ----
#pragma unroll
    for (int half = 0; half < 2; half++) {
      float ev[8], wv[8];
#pragma unroll
      for (int j = 0; j < 8; j++) {
        const int b = bg * 16 + half * 8 + j;
        ev[j] = E[(size_t)b * NN + n];
        wv[j] = wrr[(size_t)b * NN + n];
      }
#pragma unroll
      for (int j = 0; j < 8; j++) {
        const int b = bg * 16 + half * 8 + j;
        const float gri = g_sh[b] * ri_sh[b];
        const float omg = 1.f - g_sh[b];
        const float wgc = gri * ev[j] + omg * wv[j];
        float wgm = __shfl_up(wgc, 1, 64);
        float wgp = __shfl_down(wgc, 1, 64);
        if (n_l == 0)
          wgm = (n > 0) ? (gri * E[(size_t)b * NN + n - 1] + omg * wrr[(size_t)b * NN + n - 1]) : 0.f;
        if (n_l == 63)
          wgp = (n < NN - 1) ? (gri * E[(size_t)b * NN + n + 1] + omg * wrr[(size_t)b * NN + n + 1]) : 0.f;
        const float wt = s0_sh[b] * wgm + s1_sh[b] * wgc + s2_sh[b] * wgp;
        const float wp = fastPow(wt, gm_sh[b]);
        w_shT[n_l * 68 + b] = wp;
        gs_acc += wp;
      }
    }
    __syncthreads();
    // ---- gemm accumulate: thread (bq, mq): 4 b x 4 m; m1 from global/L2 ----
    const float4* __restrict__ m1p = (const float4*)(m1 + (size_t)n0 * MM);
#pragma unroll 4
    for (int nn = 0; nn < 64; nn++) {
      const float4 mv = m1p[nn * 16 + mq];
      const float4 wv4 = *((const float4*)&w_shT[nn * 68 + bq * 4]);
      acc[0].x += wv4.x * mv.x; acc[0].y += wv4.x * mv.y; acc[0].z += wv4.x * mv.z; acc[0].w += wv4.x * mv.w;
      acc[1].x += wv4.y * mv.x; acc[1].y += wv4.y * mv.y; acc[1].z += wv4.y * mv.z; acc[1].w += wv4.y * mv.w;
      acc[2].x += wv4.z * mv.x; acc[2].y += wv4.z * mv.y; acc[2].z += wv4.z * mv.z; acc[2].w += wv4.z * mv.w;
      acc[3].x += wv4.w * mv.x; acc[3].y += wv4.w * mv.y; acc[3].z += wv4.w * mv.z; acc[3].w += wv4.w * mv.w;
    }
  }
  float* pp = part + ((size_t)r * 512 + sc) * 4096;
#pragma unroll
  for (int j = 0; j < 4; j++)
    *((float4*)&pp[(bq * 4 + j) * 64 + mq * 4]) = acc[j];
  const float v = waveReduceSum(gs_acc);
  if (n_l == 0) gsred[bg] = v;
  __syncthreads();
  if (t == 0)
    atomicAdd(&GSp[(1 + r) * 1024 + (sc & 63) * 16],
              gsred[0] + gsred[1] + gsred[2] + gsred[3]);
}

// ---------------------------------------------------------------------------
// K7: reduce part[4][512][4096] + GS normalize. grid (64 b, 4 r), block 256.
// 4x the block parallelism of the old 64-block version; 256B-coalesced reads.
// ---------------------------------------------------------------------------
__global__ __launch_bounds__(256) void finalize_kernel(
    const float* __restrict__ part, const float* __restrict__ GSp,
    float* __restrict__ out)
{
  __shared__ float gs_sh;
  __shared__ float4 red[16][16];
  const int t = threadIdx.x;
  const int b = blockIdx.x, r = blockIdx.y;
  if (t < 64) {
    float v = GSp[(1 + r) * 1024 + t * 16];
    v = waveReduceSum(v);
    if (t == 0) gs_sh = v;
  }
  const int f = t & 15;       // float4 column within the 64-float m row
  const int chunk = t >> 4;   // 0..15, each sums 32 slabs
  const float4* p4 = (const float4*)part;
  const size_t base = (size_t)r * 512 * 1024 + (size_t)b * 16 + f;
  float4 sum = make_float4(0.f, 0.f, 0.f, 0.f);
#pragma unroll 8
  for (int k = chunk * 32; k < chunk * 32 + 32; k++) {
    const float4 v = p4[base + (size_t)k * 1024];
    sum.x += v.x; sum.y += v.y; sum.z += v.z; sum.w += v.w;
  }
  red[chunk][f] = sum;
  __syncthreads();
  if (t < 16) {
    float4 tot = make_float4(0.f, 0.f, 0.f, 0.f);
#pragma unroll
    for (int k = 0; k < 16; k++) {
      const float4 v = red[k][t];
      tot.x += v.x; tot.y += v.y; tot.z += v.z; tot.w += v.w;
    }
    const float inv = 1.0f / (gs_sh + 1e-5f);
    tot.x *= inv; tot.y *= inv; tot.z *= inv; tot.w *= inv;
    ((float4*)out)[b * 64 + r * 16 + t] = tot;
  }
}

// ---------------------------------------------------------------------------
extern "C" void kernel_launch(void* const* d_in, const int* in_sizes, int n_in,
                              void* d_out, int out_size, void* d_ws, size_t ws_size,
                              hipStream_t stream) {
  (void)in_sizes; (void)n_in; (void)out_size; (void)ws_size;
  const float* h_t    = (const float*)d_in[0];
  const float* ww     = (const float*)d_in[1];
  const float* wr     = (const float*)d_in[2];
  const float* memory = (const float*)d_in[3];
  const float* key_w  = (const float*)d_in[4];
  const float* key_b  = (const float*)d_in[5];
  const float* beta_w = (const float*)d_in[6];
  const float* beta_b = (const float*)d_in[7];
  const float* gate_w = (const float*)d_in[8];
  const float* gate_b = (const float*)d_in[9];
  const float* shift_w = (const float*)d_in[10];
  const float* shift_b = (const float*)d_in[11];
  const float* gamma_w = (const float*)d_in[12];
  const float* gamma_b = (const float*)d_in[13];
  const float* erase_w = (const float*)d_in[14];
  const float* erase_b = (const float*)d_in[15];
  const float* add_w   = (const float*)d_in[16];
  const float* add_b   = (const float*)d_in[17];
  const int*   bank    = (const int*)d_in[18];

  float* ws = (float*)d_ws;
  // slabs (floats): E0 @0, W0 @4M, m1 @8M, E1 @12M, smallb @16M,
  // part @20M (4 x 512 x 4096 = 8.39M floats = 33.6MB).
  float* E0   = ws;
  float* W0   = ws + 4194304;
  float* m1   = ws + 8388608;
  float* E1   = ws + 12582912;
  float* smallb = ws + 16777216;
  float* part = ws + 20971520;
  float* kn    = smallb;            // 4096
  float* e_v   = smallb + 4096;     // 4096
  float* a_v   = smallb + 8192;     // 4096
  float* betaB = smallb + 12288;    // 64
  float* g     = smallb + 12352;    // 64
  float* gam   = smallb + 12416;    // 64
  float* s     = smallb + 12480;    // 256 (192 used)
  float* RS0p  = smallb + 12800;    // 16384 (64 b x 16 slots x 16 pad)
  float* RS1p  = smallb + 29184;    // 16384
  float* GSp   = smallb + 45568;    // 5120 (5 slots x 64 x 16 pad)
  // RS0p/RS1p/GSp contiguous: zero range = smallb+12800 .. +50688

  prep_kernel<<<64, 256, 0, stream>>>(
      h_t, key_w, key_b, erase_w, erase_b, add_w, add_b,
      beta_w, beta_b, gate_w, gate_b, shift_w, shift_b, gamma_w, gamma_b,
      kn, e_v, a_v, g, gam, s, betaB, smallb + 12800);
  content_kernel<<<1024, 256, 0, stream>>>(memory, bank, kn, betaB, E0, RS0p);
  wpow_kernel<<<dim3(64, 64), 256, 0, stream>>>(E0, ww, RS0p, g, gam, s, W0, GSp, 0);
  apply_write_kernel<<<1024, 256, 0, stream>>>(W0, GSp, e_v, a_v, memory, bank, m1);
  content_kernel<<<1024, 256, 0, stream>>>(m1, nullptr, kn, betaB, E1, RS1p);
  rheads_kernel<<<dim3(512, 4), 256, 0, stream>>>(E1, wr, m1, RS1p, g, gam, s, part, GSp);
  finalize_kernel<<<dim3(64, 4), 256, 0, stream>>>(part, GSp, (float*)d_out);
}

// Round 10
// 382.767 us; speedup vs baseline: 1.0822x; 1.0822x over previous
//
#include <hip/hip_runtime.h>

#define NN 65536
#define BB 64
#define HH 1024
#define MM 64
#define RR 4

__device__ __forceinline__ float waveReduceSum(float v) {
#pragma unroll
  for (int off = 32; off > 0; off >>= 1) v += __shfl_xor(v, off, 64);
  return v;
}

__device__ __forceinline__ float fastPow(float wt, float p) {
  return __expf(p * __logf(wt));
}

// ---------------------------------------------------------------------------
// K1: prep, split over grid (64 b, 4 parts). part 0/1/2: one 1024x64 GEMM
// each (key->kn / erase / add); part 3: zero-init RS/GS partials + 6 small
// dots. 4x the parallelism of the old single-block-per-b version (which ran
// 1 wave/SIMD on 25% of the GPU with 768 serial MACs/thread).
// ---------------------------------------------------------------------------
__global__ __launch_bounds__(256) void prep_kernel(
    const float* __restrict__ h_t,
    const float* __restrict__ key_w, const float* __restrict__ key_b,
    const float* __restrict__ erase_w, const float* __restrict__ erase_b,
    const float* __restrict__ add_w, const float* __restrict__ add_b,
    const float* __restrict__ beta_w, const float* __restrict__ beta_b,
    const float* __restrict__ gate_w, const float* __restrict__ gate_b,
    const float* __restrict__ shift_w, const float* __restrict__ shift_b,
    const float* __restrict__ gamma_w, const float* __restrict__ gamma_b,
    float* __restrict__ kn, float* __restrict__ e_v, float* __restrict__ a_v,
    float* __restrict__ g, float* __restrict__ gamma_, float* __restrict__ s,
    float* __restrict__ betaGlob, float* __restrict__ zbase)
{
  const int b = blockIdx.x;
  const int part = blockIdx.y;
  const int t = threadIdx.x;

  if (part == 3) {
    // zero-init RS0p/RS1p/GSp (37888 floats), 64 blocks x 256 threads
    for (int i = b * 256 + t; i < 37888; i += 16384) zbase[i] = 0.f;
    // six small dots on one wave (lanes 192..255), h from global (coalesced)
    if (t >= 192) {
      const int lane = t - 192;
      float o0 = 0.f, o1 = 0.f, o2 = 0.f, o3 = 0.f, o4 = 0.f, o5 = 0.f;
#pragma unroll 4
      for (int k = 0; k < 16; k++) {
        const int hh = lane + k * 64;
        const float hv = h_t[(size_t)b * HH + hh];
        o0 += hv * beta_w[hh];
        o1 += hv * gate_w[hh];
        o2 += hv * gamma_w[hh];
        o3 += hv * shift_w[hh * 3 + 0];
        o4 += hv * shift_w[hh * 3 + 1];
        o5 += hv * shift_w[hh * 3 + 2];
      }
      o0 = waveReduceSum(o0); o1 = waveReduceSum(o1); o2 = waveReduceSum(o2);
      o3 = waveReduceSum(o3); o4 = waveReduceSum(o4); o5 = waveReduceSum(o5);
      if (lane == 0) {
        betaGlob[b] = fmaxf(o0 + beta_b[0], 0.f);
        g[b]        = fminf(fmaxf(o1 + gate_b[0], 0.f), 1.f);
        gamma_[b]   = 1.0f + fmaxf(o2 + gamma_b[0], 0.f);
        const float l0 = o3 + shift_b[0], l1 = o4 + shift_b[1], l2 = o5 + shift_b[2];
        const float mx = fmaxf(l0, fmaxf(l1, l2));
        const float e0 = __expf(l0 - mx), e1 = __expf(l1 - mx), e2 = __expf(l2 - mx);
        const float inv = 1.f / (e0 + e1 + e2);
        s[b * 3 + 0] = e0 * inv; s[b * 3 + 1] = e1 * inv; s[b * 3 + 2] = e2 * inv;
      }
    }
    return;
  }

  __shared__ float h_sh[HH];
  __shared__ float red[64][4];
  __shared__ float k_sh[64];
  ((float4*)h_sh)[t] = ((const float4*)(h_t + (size_t)b * HH))[t];
  __syncthreads();
  const int c = t & 63, q = t >> 6;
  const float* __restrict__ Wm = (part == 0) ? key_w : ((part == 1) ? erase_w : add_w);
  float d = 0.f;
#pragma unroll 8
  for (int i = 0; i < 256; i++)
    d += h_sh[q * 256 + i] * Wm[(q * 256 + i) * 64 + c];
  red[c][q] = d;
  __syncthreads();
  if (t < 64) {
    const float v = red[t][0] + red[t][1] + red[t][2] + red[t][3];
    if (part == 0)      k_sh[t] = fminf(fmaxf(v + key_b[t], 0.f), 1.f);
    else if (part == 1) e_v[b * 64 + t] = fminf(fmaxf(v + erase_b[t], 0.f), 1.f);
    else                a_v[b * 64 + t] = fminf(fmaxf(v + add_b[t], 0.f), 1.f);
  }
  if (part == 0) {
    __syncthreads();
    if (t < 64) {
      float ss = 0.f;
      for (int j = 0; j < 64; j++) ss += k_sh[j] * k_sh[j];
      kn[b * 64 + t] = k_sh[t] / (sqrtf(ss) + 1e-8f);
    }
  }
}

// ---------------------------------------------------------------------------
// K2 / K5: content addressing, row-read-once layout. grid 1024, block 256.
// ---------------------------------------------------------------------------
__global__ __launch_bounds__(256) void content_kernel(
    const float* __restrict__ mem, const int* __restrict__ bank,
    const float* __restrict__ kn, const float* __restrict__ beta,
    float* __restrict__ E, float* __restrict__ RSp)
{
  const float* Mrow = mem + (bank ? ((size_t)(*bank) * (size_t)NN * MM) : (size_t)0);
  const int t = threadIdx.x;
  const int lane = t & 63;
  const int n = blockIdx.x * 64 + lane;
  const int b0 = (t >> 6) * 16;

  float4 row[16];
  const float4* rp = (const float4*)(Mrow + (size_t)n * MM);
#pragma unroll
  for (int q = 0; q < 16; q++) row[q] = rp[q];
  float ss = 0.f;
#pragma unroll
  for (int q = 0; q < 16; q++)
    ss += row[q].x * row[q].x + row[q].y * row[q].y + row[q].z * row[q].z + row[q].w * row[q].w;
  const float rinv = 1.0f / (sqrtf(ss) + 1e-8f);

  __shared__ float accs[64];
  for (int i = 0; i < 16; i++) {
    const int rb = __builtin_amdgcn_readfirstlane(b0 + i);
    const float4* kp = (const float4*)(kn + rb * 64);
    float dot = 0.f;
#pragma unroll
    for (int q = 0; q < 16; q++) {
      const float4 kq = kp[q];
      dot += kq.x * row[q].x + kq.y * row[q].y + kq.z * row[q].z + kq.w * row[q].w;
    }
    const float e = __expf(beta[rb] * dot * rinv);
    E[(size_t)rb * NN + n] = e;
    const float r = waveReduceSum(e);
    if (lane == 0) accs[b0 + i] = r;
  }
  __syncthreads();
  if (t < 64) atomicAdd(&RSp[t * 256 + (blockIdx.x & 15) * 16], accs[t]);
}

// ---------------------------------------------------------------------------
// K3: w_pow producer for the WRITE head, float4-vectorized. grid (64, 64).
// ---------------------------------------------------------------------------
__global__ __launch_bounds__(256) void wpow_kernel(
    const float* __restrict__ E, const float* __restrict__ wprev,
    const float* __restrict__ RSp, const float* __restrict__ g,
    const float* __restrict__ gamma_, const float* __restrict__ s,
    float* __restrict__ W, float* __restrict__ GSp, int slot)
{
  const int b = blockIdx.y;
  const float gb = g[b], gmb = gamma_[b];
  const float s0 = s[b * 3], s1 = s[b * 3 + 1], s2 = s[b * 3 + 2];
  float rs = 0.f;
#pragma unroll
  for (int j = 0; j < 16; j++) rs += RSp[b * 256 + j * 16];
  const float gri = gb / rs;
  const float omg = 1.f - gb;
  const float* Eb = E + (size_t)b * NN;
  const float* wb = wprev + (size_t)b * NN;
  const int t = threadIdx.x;
  const int lane = t & 63;
  const int n0 = blockIdx.x * 1024 + t * 4;
  const float4 e4 = *((const float4*)(Eb + n0));
  const float4 w4 = *((const float4*)(wb + n0));
  const float wg0 = gri * e4.x + omg * w4.x;
  const float wg1 = gri * e4.y + omg * w4.y;
  const float wg2 = gri * e4.z + omg * w4.z;
  const float wg3 = gri * e4.w + omg * w4.w;
  float wgL = __shfl_up(wg3, 1, 64);
  float wgR = __shfl_down(wg0, 1, 64);
  if (lane == 0)  wgL = (n0 > 0) ? (gri * Eb[n0 - 1] + omg * wb[n0 - 1]) : 0.f;
  if (lane == 63) wgR = (n0 + 4 < NN) ? (gri * Eb[n0 + 4] + omg * wb[n0 + 4]) : 0.f;
  float4 wp;
  wp.x = fastPow(s0 * wgL + s1 * wg0 + s2 * wg1, gmb);
  wp.y = fastPow(s0 * wg0 + s1 * wg1 + s2 * wg2, gmb);
  wp.z = fastPow(s0 * wg1 + s1 * wg2 + s2 * wg3, gmb);
  wp.w = fastPow(s0 * wg2 + s1 * wg3 + s2 * wgR, gmb);
  *((float4*)(W + (size_t)b * NN + n0)) = wp;
  const float acc = wp.x + wp.y + wp.z + wp.w;
  __shared__ float wsum[4];
  const float w = waveReduceSum(acc);
  if (lane == 0) wsum[t >> 6] = w;
  __syncthreads();
  if (t == 0)
    atomicAdd(&GSp[slot * 1024 + b * 16], wsum[0] + wsum[1] + wsum[2] + wsum[3]);
}

// ---------------------------------------------------------------------------
// K4: apply write head. grid 1024 (64-n), block 256. Only cw staged in LDS.
// ---------------------------------------------------------------------------
__global__ __launch_bounds__(256) void apply_write_kernel(
    const float* __restrict__ W0, const float* __restrict__ GSp,
    const float* __restrict__ e_v, const float* __restrict__ a_v,
    const float* __restrict__ memory, const int* __restrict__ bank,
    float* __restrict__ m1)
{
  __shared__ float cw[64 * 68];
  const int t = threadIdx.x;
  const int n0 = blockIdx.x * 64;
  float gs = 0.f;
#pragma unroll
  for (int j = 0; j < 64; j++) gs += GSp[j * 16];
  const float invGS = 1.0f / (gs + 1e-5f);
#pragma unroll
  for (int rep = 0; rep < 4; rep++) {
    const int idx = rep * 256 + t;
    const int b = idx >> 4, nc = idx & 15;
    float4 v = *((const float4*)(W0 + (size_t)b * NN + n0 + nc * 4));
    v.x *= invGS; v.y *= invGS; v.z *= invGS; v.w *= invGS;
    *((float4*)&cw[b * 68 + nc * 4]) = v;
  }
  __syncthreads();
  const int nq = t >> 4, mq = t & 15;
  float4 er0 = make_float4(0.f,0.f,0.f,0.f), er1 = er0, er2 = er0, er3 = er0;
  float4 ad0 = er0, ad1 = er0, ad2 = er0, ad3 = er0;
#pragma unroll 4
  for (int b = 0; b < 64; b++) {
    const float4 cwv = *((const float4*)&cw[b * 68 + nq * 4]);
    const float4 evv = ((const float4*)(e_v + b * 64))[mq];
    const float4 avv = ((const float4*)(a_v + b * 64))[mq];
    er0.x += cwv.x * evv.x; er0.y += cwv.x * evv.y; er0.z += cwv.x * evv.z; er0.w += cwv.x * evv.w;
    er1.x += cwv.y * evv.x; er1.y += cwv.y * evv.y; er1.z += cwv.y * evv.z; er1.w += cwv.y * evv.w;
    er2.x += cwv.z * evv.x; er2.y += cwv.z * evv.y; er2.z += cwv.z * evv.z; er2.w += cwv.z * evv.w;
    er3.x += cwv.w * evv.x; er3.y += cwv.w * evv.y; er3.z += cwv.w * evv.z; er3.w += cwv.w * evv.w;
    ad0.x += cwv.x * avv.x; ad0.y += cwv.x * avv.y; ad0.z += cwv.x * avv.z; ad0.w += cwv.x * avv.w;
    ad1.x += cwv.y * avv.x; ad1.y += cwv.y * avv.y; ad1.z += cwv.y * avv.z; ad1.w += cwv.y * avv.w;
    ad2.x += cwv.z * avv.x; ad2.y += cwv.z * avv.y; ad2.z += cwv.z * avv.z; ad2.w += cwv.z * avv.w;
    ad3.x += cwv.w * avv.x; ad3.y += cwv.w * avv.y; ad3.z += cwv.w * avv.z; ad3.w += cwv.w * avv.w;
  }
  const float* M0 = memory + (size_t)(*bank) * (size_t)NN * MM;
#pragma unroll
  for (int i = 0; i < 4; i++) {
    const int n = n0 + nq * 4 + i;
    const float4 mv = ((const float4*)(M0 + (size_t)n * MM))[mq];
    const float4 er = (i == 0) ? er0 : (i == 1) ? er1 : (i == 2) ? er2 : er3;
    const float4 ad = (i == 0) ? ad0 : (i == 1) ? ad1 : (i == 2) ? ad2 : ad3;
    float4 o;
    o.x = mv.x * (1.f - er.x) + ad.x;
    o.y = mv.y * (1.f - er.y) + ad.y;
    o.z = mv.z * (1.f - er.z) + ad.z;
    o.w = mv.w * (1.f - er.w) + ad.w;
    ((float4*)(m1 + (size_t)n * MM))[mq] = o;
  }
}

// ---------------------------------------------------------------------------
// K6: per-r fused wpow+gemm — FROZEN round-3/8 structure (123us, occ 43%,
// VGPR 64). grid (512, 4). Do not trade occupancy for per-thread work:
// keep VGPR <= 64, LDS <= 19.4KB (R1/R4/R5/R7 all regressed).
// ---------------------------------------------------------------------------
__global__ __launch_bounds__(256) void rheads_kernel(
    const float* __restrict__ E, const float* __restrict__ wr,
    const float* __restrict__ m1, const float* __restrict__ RSp,
    const float* __restrict__ g, const float* __restrict__ gamma_,
    const float* __restrict__ s,
    float* __restrict__ part, float* __restrict__ GSp)
{
  __shared__ float g_sh[64], gm_sh[64], ri_sh[64];
  __shared__ float s0_sh[64], s1_sh[64], s2_sh[64];
  __shared__ float w_shT[64 * 68];   // [n_local][b], pad 68
  __shared__ float gsred[4];
  const int sc = blockIdx.x, r = blockIdx.y;
  const int t = threadIdx.x;
  if (t < 64) {
    float rs = 0.f;
#pragma unroll
    for (int j = 0; j < 16; j++) rs += RSp[t * 256 + j * 16];
    ri_sh[t] = 1.0f / rs;
    g_sh[t] = g[t];
    gm_sh[t] = gamma_[t];
    s0_sh[t] = s[t * 3 + 0];
    s1_sh[t] = s[t * 3 + 1];
    s2_sh[t] = s[t * 3 + 2];
  }
  __syncthreads();
  const int n_l = t & 63, bg = t >> 6;
  const int bq = t >> 4, mq = t & 15;
  const float* __restrict__ wrr = wr + (size_t)r * BB * NN;
  float4 acc[4];
#pragma unroll
  for (int j = 0; j < 4; j++) acc[j] = make_float4(0.f, 0.f, 0.f, 0.f);
  float gs_acc = 0.f;

  for (int st = 0; st < 2; st++) {
    if (st) __syncthreads();  // gemm finished reading w_shT
    const int n0 = (sc * 2 + st) * 64;
    const int n = n0 + n_l;
    // ---- produce w tile: wave bg owns b in [bg*16, bg*16+16) ----
#pragma unroll
    for (int half = 0; half < 2; half++) {
      float ev[8], wv[8];
#pragma unroll
      for (int j = 0; j < 8; j++) {
        const int b = bg * 16 + half * 8 + j;
        ev[j] = E[(size_t)b * NN + n];
        wv[j] = wrr[(size_t)b * NN + n];
      }
#pragma unroll
      for (int j = 0; j < 8; j++) {
        const int b = bg * 16 + half * 8 + j;
        const float gri = g_sh[b] * ri_sh[b];
        const float omg = 1.f - g_sh[b];
        const float wgc = gri * ev[j] + omg * wv[j];
        float wgm = __shfl_up(wgc, 1, 64);
        float wgp = __shfl_down(wgc, 1, 64);
        if (n_l == 0)
          wgm = (n > 0) ? (gri * E[(size_t)b * NN + n - 1] + omg * wrr[(size_t)b * NN + n - 1]) : 0.f;
        if (n_l == 63)
          wgp = (n < NN - 1) ? (gri * E[(size_t)b * NN + n + 1] + omg * wrr[(size_t)b * NN + n + 1]) : 0.f;
        const float wt = s0_sh[b] * wgm + s1_sh[b] * wgc + s2_sh[b] * wgp;
        const float wp = fastPow(wt, gm_sh[b]);
        w_shT[n_l * 68 + b] = wp;
        gs_acc += wp;
      }
    }
    __syncthreads();
    // ---- gemm accumulate: thread (bq, mq): 4 b x 4 m; m1 from global/L2 ----
    const float4* __restrict__ m1p = (const float4*)(m1 + (size_t)n0 * MM);
#pragma unroll 4
    for (int nn = 0; nn < 64; nn++) {
      const float4 mv = m1p[nn * 16 + mq];
      const float4 wv4 = *((const float4*)&w_shT[nn * 68 + bq * 4]);
      acc[0].x += wv4.x * mv.x; acc[0].y += wv4.x * mv.y; acc[0].z += wv4.x * mv.z; acc[0].w += wv4.x * mv.w;
      acc[1].x += wv4.y * mv.x; acc[1].y += wv4.y * mv.y; acc[1].z += wv4.y * mv.z; acc[1].w += wv4.y * mv.w;
      acc[2].x += wv4.z * mv.x; acc[2].y += wv4.z * mv.y; acc[2].z += wv4.z * mv.z; acc[2].w += wv4.z * mv.w;
      acc[3].x += wv4.w * mv.x; acc[3].y += wv4.w * mv.y; acc[3].z += wv4.w * mv.z; acc[3].w += wv4.w * mv.w;
    }
  }
  float* pp = part + ((size_t)r * 512 + sc) * 4096;
#pragma unroll
  for (int j = 0; j < 4; j++)
    *((float4*)&pp[(bq * 4 + j) * 64 + mq * 4]) = acc[j];
  const float v = waveReduceSum(gs_acc);
  if (n_l == 0) gsred[bg] = v;
  __syncthreads();
  if (t == 0)
    atomicAdd(&GSp[(1 + r) * 1024 + (sc & 63) * 16],
              gsred[0] + gsred[1] + gsred[2] + gsred[3]);
}

// ---------------------------------------------------------------------------
// K7: reduce part[4][512][4096] + GS normalize. grid 64 (b), block 1024.
// ---------------------------------------------------------------------------
__global__ __launch_bounds__(1024) void finalize_kernel(
    const float* __restrict__ part, const float* __restrict__ GSp,
    float* __restrict__ out)
{
  __shared__ float gs_sh[4];
  __shared__ float red[4][256];
  const int t = threadIdx.x;
  if (t < 256) {
    const int wv = t >> 6, ln = t & 63;
    float v = GSp[(1 + wv) * 1024 + ln * 16];
    v = waveReduceSum(v);
    if (ln == 0) gs_sh[wv] = v;
  }
  const int b = blockIdx.x;
  const int q = t >> 8;        // slab quarter 0..3 (128 slabs each)
  const int e = t & 255;       // r*64 + m
  const int r = e >> 6, m = e & 63;
  float sum = 0.f;
  const float* pp = part + (size_t)r * 512 * 4096 + (size_t)b * 64 + m;
#pragma unroll 8
  for (int k = q * 128; k < q * 128 + 128; k++)
    sum += pp[(size_t)k * 4096];
  red[q][e] = sum;
  __syncthreads();
  if (t < 256) {
    const float tot = red[0][t] + red[1][t] + red[2][t] + red[3][t];
    out[b * 256 + t] = tot / (gs_sh[t >> 6] + 1e-5f);
  }
}

// ---------------------------------------------------------------------------
extern "C" void kernel_launch(void* const* d_in, const int* in_sizes, int n_in,
                              void* d_out, int out_size, void* d_ws, size_t ws_size,
                              hipStream_t stream) {
  (void)in_sizes; (void)n_in; (void)out_size; (void)ws_size;
  const float* h_t    = (const float*)d_in[0];
  const float* ww     = (const float*)d_in[1];
  const float* wr     = (const float*)d_in[2];
  const float* memory = (const float*)d_in[3];
  const float* key_w  = (const float*)d_in[4];
  const float* key_b  = (const float*)d_in[5];
  const float* beta_w = (const float*)d_in[6];
  const float* beta_b = (const float*)d_in[7];
  const float* gate_w = (const float*)d_in[8];
  const float* gate_b = (const float*)d_in[9];
  const float* shift_w = (const float*)d_in[10];
  const float* shift_b = (const float*)d_in[11];
  const float* gamma_w = (const float*)d_in[12];
  const float* gamma_b = (const float*)d_in[13];
  const float* erase_w = (const float*)d_in[14];
  const float* erase_b = (const float*)d_in[15];
  const float* add_w   = (const float*)d_in[16];
  const float* add_b   = (const float*)d_in[17];
  const int*   bank    = (const int*)d_in[18];

  float* ws = (float*)d_ws;
  // slabs (floats): E0 @0, W0 @4M, m1 @8M, E1 @12M, smallb @16M,
  // part @20M (4 x 512 x 4096 = 8.39M floats = 33.6MB).
  float* E0   = ws;
  float* W0   = ws + 4194304;
  float* m1   = ws + 8388608;
  float* E1   = ws + 12582912;
  float* smallb = ws + 16777216;
  float* part = ws + 20971520;
  float* kn    = smallb;            // 4096
  float* e_v   = smallb + 4096;     // 4096
  float* a_v   = smallb + 8192;     // 4096
  float* betaB = smallb + 12288;    // 64
  float* g     = smallb + 12352;    // 64
  float* gam   = smallb + 12416;    // 64
  float* s     = smallb + 12480;    // 256 (192 used)
  float* RS0p  = smallb + 12800;    // 16384 (64 b x 16 slots x 16 pad)
  float* RS1p  = smallb + 29184;    // 16384
  float* GSp   = smallb + 45568;    // 5120 (5 slots x 64 x 16 pad)
  // RS0p/RS1p/GSp contiguous: zero range = smallb+12800 .. +50688

  prep_kernel<<<dim3(64, 4), 256, 0, stream>>>(
      h_t, key_w, key_b, erase_w, erase_b, add_w, add_b,
      beta_w, beta_b, gate_w, gate_b, shift_w, shift_b, gamma_w, gamma_b,
      kn, e_v, a_v, g, gam, s, betaB, smallb + 12800);
  content_kernel<<<1024, 256, 0, stream>>>(memory, bank, kn, betaB, E0, RS0p);
  wpow_kernel<<<dim3(64, 64), 256, 0, stream>>>(E0, ww, RS0p, g, gam, s, W0, GSp, 0);
  apply_write_kernel<<<1024, 256, 0, stream>>>(W0, GSp, e_v, a_v, memory, bank, m1);
  content_kernel<<<1024, 256, 0, stream>>>(m1, nullptr, kn, betaB, E1, RS1p);
  rheads_kernel<<<dim3(512, 4), 256, 0, stream>>>(E1, wr, m1, RS1p, g, gam, s, part, GSp);
  finalize_kernel<<<64, 1024, 0, stream>>>(part, GSp, (float*)d_out);
}

// Round 11
// 372.025 us; speedup vs baseline: 1.1135x; 1.0289x over previous
//
#include <hip/hip_runtime.h>

#define NN 65536
#define BB 64
#define HH 1024
#define MM 64
#define RR 4

__device__ __forceinline__ float waveReduceSum(float v) {
#pragma unroll
  for (int off = 32; off > 0; off >>= 1) v += __shfl_xor(v, off, 64);
  return v;
}

__device__ __forceinline__ float fastPow(float wt, float p) {
  return __expf(p * __logf(wt));
}

// ---------------------------------------------------------------------------
// K1: prep, split over grid (64 b, 4 parts). part 0/1/2: one 1024x64 GEMM
// each (key->kn / erase / add); part 3: zero-init RS/GS partials + 6 small
// dots. (R10: this split was -30us vs the single-block-per-b version.)
// ---------------------------------------------------------------------------
__global__ __launch_bounds__(256) void prep_kernel(
    const float* __restrict__ h_t,
    const float* __restrict__ key_w, const float* __restrict__ key_b,
    const float* __restrict__ erase_w, const float* __restrict__ erase_b,
    const float* __restrict__ add_w, const float* __restrict__ add_b,
    const float* __restrict__ beta_w, const float* __restrict__ beta_b,
    const float* __restrict__ gate_w, const float* __restrict__ gate_b,
    const float* __restrict__ shift_w, const float* __restrict__ shift_b,
    const float* __restrict__ gamma_w, const float* __restrict__ gamma_b,
    float* __restrict__ kn, float* __restrict__ e_v, float* __restrict__ a_v,
    float* __restrict__ g, float* __restrict__ gamma_, float* __restrict__ s,
    float* __restrict__ betaGlob, float* __restrict__ zbase)
{
  const int b = blockIdx.x;
  const int part = blockIdx.y;
  const int t = threadIdx.x;

  if (part == 3) {
    for (int i = b * 256 + t; i < 37888; i += 16384) zbase[i] = 0.f;
    if (t >= 192) {
      const int lane = t - 192;
      float o0 = 0.f, o1 = 0.f, o2 = 0.f, o3 = 0.f, o4 = 0.f, o5 = 0.f;
#pragma unroll 4
      for (int k = 0; k < 16; k++) {
        const int hh = lane + k * 64;
        const float hv = h_t[(size_t)b * HH + hh];
        o0 += hv * beta_w[hh];
        o1 += hv * gate_w[hh];
        o2 += hv * gamma_w[hh];
        o3 += hv * shift_w[hh * 3 + 0];
        o4 += hv * shift_w[hh * 3 + 1];
        o5 += hv * shift_w[hh * 3 + 2];
      }
      o0 = waveReduceSum(o0); o1 = waveReduceSum(o1); o2 = waveReduceSum(o2);
      o3 = waveReduceSum(o3); o4 = waveReduceSum(o4); o5 = waveReduceSum(o5);
      if (lane == 0) {
        betaGlob[b] = fmaxf(o0 + beta_b[0], 0.f);
        g[b]        = fminf(fmaxf(o1 + gate_b[0], 0.f), 1.f);
        gamma_[b]   = 1.0f + fmaxf(o2 + gamma_b[0], 0.f);
        const float l0 = o3 + shift_b[0], l1 = o4 + shift_b[1], l2 = o5 + shift_b[2];
        const float mx = fmaxf(l0, fmaxf(l1, l2));
        const float e0 = __expf(l0 - mx), e1 = __expf(l1 - mx), e2 = __expf(l2 - mx);
        const float inv = 1.f / (e0 + e1 + e2);
        s[b * 3 + 0] = e0 * inv; s[b * 3 + 1] = e1 * inv; s[b * 3 + 2] = e2 * inv;
      }
    }
    return;
  }

  __shared__ float h_sh[HH];
  __shared__ float red[64][4];
  __shared__ float k_sh[64];
  ((float4*)h_sh)[t] = ((const float4*)(h_t + (size_t)b * HH))[t];
  __syncthreads();
  const int c = t & 63, q = t >> 6;
  const float* __restrict__ Wm = (part == 0) ? key_w : ((part == 1) ? erase_w : add_w);
  float d = 0.f;
#pragma unroll 8
  for (int i = 0; i < 256; i++)
    d += h_sh[q * 256 + i] * Wm[(q * 256 + i) * 64 + c];
  red[c][q] = d;
  __syncthreads();
  if (t < 64) {
    const float v = red[t][0] + red[t][1] + red[t][2] + red[t][3];
    if (part == 0)      k_sh[t] = fminf(fmaxf(v + key_b[t], 0.f), 1.f);
    else if (part == 1) e_v[b * 64 + t] = fminf(fmaxf(v + erase_b[t], 0.f), 1.f);
    else                a_v[b * 64 + t] = fminf(fmaxf(v + add_b[t], 0.f), 1.f);
  }
  if (part == 0) {
    __syncthreads();
    if (t < 64) {
      float ss = 0.f;
      for (int j = 0; j < 64; j++) ss += k_sh[j] * k_sh[j];
      kn[b * 64 + t] = k_sh[t] / (sqrtf(ss) + 1e-8f);
    }
  }
}

// ---------------------------------------------------------------------------
// K2 / K5: content addressing. grid (1024, 2), block 256.
// y selects a 32-b half; each wave handles 8 b (was 16) -> serial
// dot+waveReduce chain halves, block parallelism doubles. The extra
// row re-read (2 blocks per n-tile) is L2/L3-resident.
// ---------------------------------------------------------------------------
__global__ __launch_bounds__(256) void content_kernel(
    const float* __restrict__ mem, const int* __restrict__ bank,
    const float* __restrict__ kn, const float* __restrict__ beta,
    float* __restrict__ E, float* __restrict__ RSp)
{
  const float* Mrow = mem + (bank ? ((size_t)(*bank) * (size_t)NN * MM) : (size_t)0);
  const int t = threadIdx.x;
  const int lane = t & 63;
  const int n = blockIdx.x * 64 + lane;
  const int bh = blockIdx.y * 32;
  const int b0 = bh + (t >> 6) * 8;

  float4 row[16];
  const float4* rp = (const float4*)(Mrow + (size_t)n * MM);
#pragma unroll
  for (int q = 0; q < 16; q++) row[q] = rp[q];
  float ss = 0.f;
#pragma unroll
  for (int q = 0; q < 16; q++)
    ss += row[q].x * row[q].x + row[q].y * row[q].y + row[q].z * row[q].z + row[q].w * row[q].w;
  const float rinv = 1.0f / (sqrtf(ss) + 1e-8f);

  __shared__ float accs[32];
  for (int i = 0; i < 8; i++) {
    const int rb = __builtin_amdgcn_readfirstlane(b0 + i);
    const float4* kp = (const float4*)(kn + rb * 64);
    float dot = 0.f;
#pragma unroll
    for (int q = 0; q < 16; q++) {
      const float4 kq = kp[q];
      dot += kq.x * row[q].x + kq.y * row[q].y + kq.z * row[q].z + kq.w * row[q].w;
    }
    const float e = __expf(beta[rb] * dot * rinv);
    E[(size_t)rb * NN + n] = e;
    const float r = waveReduceSum(e);
    if (lane == 0) accs[(t >> 6) * 8 + i] = r;
  }
  __syncthreads();
  if (t < 32)
    atomicAdd(&RSp[(bh + t) * 256 + (blockIdx.x & 15) * 16], accs[t]);
}

// ---------------------------------------------------------------------------
// K3: w_pow producer for the WRITE head, float4-vectorized. grid (64, 64).
// ---------------------------------------------------------------------------
__global__ __launch_bounds__(256) void wpow_kernel(
    const float* __restrict__ E, const float* __restrict__ wprev,
    const float* __restrict__ RSp, const float* __restrict__ g,
    const float* __restrict__ gamma_, const float* __restrict__ s,
    float* __restrict__ W, float* __restrict__ GSp, int slot)
{
  const int b = blockIdx.y;
  const float gb = g[b], gmb = gamma_[b];
  const float s0 = s[b * 3], s1 = s[b * 3 + 1], s2 = s[b * 3 + 2];
  float rs = 0.f;
#pragma unroll
  for (int j = 0; j < 16; j++) rs += RSp[b * 256 + j * 16];
  const float gri = gb / rs;
  const float omg = 1.f - gb;
  const float* Eb = E + (size_t)b * NN;
  const float* wb = wprev + (size_t)b * NN;
  const int t = threadIdx.x;
  const int lane = t & 63;
  const int n0 = blockIdx.x * 1024 + t * 4;
  const float4 e4 = *((const float4*)(Eb + n0));
  const float4 w4 = *((const float4*)(wb + n0));
  const float wg0 = gri * e4.x + omg * w4.x;
  const float wg1 = gri * e4.y + omg * w4.y;
  const float wg2 = gri * e4.z + omg * w4.z;
  const float wg3 = gri * e4.w + omg * w4.w;
  float wgL = __shfl_up(wg3, 1, 64);
  float wgR = __shfl_down(wg0, 1, 64);
  if (lane == 0)  wgL = (n0 > 0) ? (gri * Eb[n0 - 1] + omg * wb[n0 - 1]) : 0.f;
  if (lane == 63) wgR = (n0 + 4 < NN) ? (gri * Eb[n0 + 4] + omg * wb[n0 + 4]) : 0.f;
  float4 wp;
  wp.x = fastPow(s0 * wgL + s1 * wg0 + s2 * wg1, gmb);
  wp.y = fastPow(s0 * wg0 + s1 * wg1 + s2 * wg2, gmb);
  wp.z = fastPow(s0 * wg1 + s1 * wg2 + s2 * wg3, gmb);
  wp.w = fastPow(s0 * wg2 + s1 * wg3 + s2 * wgR, gmb);
  *((float4*)(W + (size_t)b * NN + n0)) = wp;
  const float acc = wp.x + wp.y + wp.z + wp.w;
  __shared__ float wsum[4];
  const float w = waveReduceSum(acc);
  if (lane == 0) wsum[t >> 6] = w;
  __syncthreads();
  if (t == 0)
    atomicAdd(&GSp[slot * 1024 + b * 16], wsum[0] + wsum[1] + wsum[2] + wsum[3]);
}

// ---------------------------------------------------------------------------
// K4: apply write head. grid 1024 (64-n), block 256. Only cw staged in LDS.
// ---------------------------------------------------------------------------
__global__ __launch_bounds__(256) void apply_write_kernel(
    const float* __restrict__ W0, const float* __restrict__ GSp,
    const float* __restrict__ e_v, const float* __restrict__ a_v,
    const float* __restrict__ memory, const int* __restrict__ bank,
    float* __restrict__ m1)
{
  __shared__ float cw[64 * 68];
  const int t = threadIdx.x;
  const int n0 = blockIdx.x * 64;
  float gs = 0.f;
#pragma unroll
  for (int j = 0; j < 64; j++) gs += GSp[j * 16];
  const float invGS = 1.0f / (gs + 1e-5f);
#pragma unroll
  for (int rep = 0; rep < 4; rep++) {
    const int idx = rep * 256 + t;
    const int b = idx >> 4, nc = idx & 15;
    float4 v = *((const float4*)(W0 + (size_t)b * NN + n0 + nc * 4));
    v.x *= invGS; v.y *= invGS; v.z *= invGS; v.w *= invGS;
    *((float4*)&cw[b * 68 + nc * 4]) = v;
  }
  __syncthreads();
  const int nq = t >> 4, mq = t & 15;
  float4 er0 = make_float4(0.f,0.f,0.f,0.f), er1 = er0, er2 = er0, er3 = er0;
  float4 ad0 = er0, ad1 = er0, ad2 = er0, ad3 = er0;
#pragma unroll 4
  for (int b = 0; b < 64; b++) {
    const float4 cwv = *((const float4*)&cw[b * 68 + nq * 4]);
    const float4 evv = ((const float4*)(e_v + b * 64))[mq];
    const float4 avv = ((const float4*)(a_v + b * 64))[mq];
    er0.x += cwv.x * evv.x; er0.y += cwv.x * evv.y; er0.z += cwv.x * evv.z; er0.w += cwv.x * evv.w;
    er1.x += cwv.y * evv.x; er1.y += cwv.y * evv.y; er1.z += cwv.y * evv.z; er1.w += cwv.y * evv.w;
    er2.x += cwv.z * evv.x; er2.y += cwv.z * evv.y; er2.z += cwv.z * evv.z; er2.w += cwv.z * evv.w;
    er3.x += cwv.w * evv.x; er3.y += cwv.w * evv.y; er3.z += cwv.w * evv.z; er3.w += cwv.w * evv.w;
    ad0.x += cwv.x * avv.x; ad0.y += cwv.x * avv.y; ad0.z += cwv.x * avv.z; ad0.w += cwv.x * avv.w;
    ad1.x += cwv.y * avv.x; ad1.y += cwv.y * avv.y; ad1.z += cwv.y * avv.z; ad1.w += cwv.y * avv.w;
    ad2.x += cwv.z * avv.x; ad2.y += cwv.z * avv.y; ad2.z += cwv.z * avv.z; ad2.w += cwv.z * avv.w;
    ad3.x += cwv.w * avv.x; ad3.y += cwv.w * avv.y; ad3.z += cwv.w * avv.z; ad3.w += cwv.w * avv.w;
  }
  const float* M0 = memory + (size_t)(*bank) * (size_t)NN * MM;
#pragma unroll
  for (int i = 0; i < 4; i++) {
    const int n = n0 + nq * 4 + i;
    const float4 mv = ((const float4*)(M0 + (size_t)n * MM))[mq];
    const float4 er = (i == 0) ? er0 : (i == 1) ? er1 : (i == 2) ? er2 : er3;
    const float4 ad = (i == 0) ? ad0 : (i == 1) ? ad1 : (i == 2) ? ad2 : ad3;
    float4 o;
    o.x = mv.x * (1.f - er.x) + ad.x;
    o.y = mv.y * (1.f - er.y) + ad.y;
    o.z = mv.z * (1.f - er.z) + ad.z;
    o.w = mv.w * (1.f - er.w) + ad.w;
    ((float4*)(m1 + (size_t)n * MM))[mq] = o;
  }
}

// ---------------------------------------------------------------------------
// K6: per-r fused wpow+gemm — FROZEN round-3/8 structure (123us, occ 43%,
// VGPR 64). grid (512, 4). Do not trade occupancy for per-thread work:
// keep VGPR <= 64, LDS <= 19.4KB (R1/R4/R5/R7 all regressed).
// ---------------------------------------------------------------------------
__global__ __launch_bounds__(256) void rheads_kernel(
    const float* __restrict__ E, const float* __restrict__ wr,
    const float* __restrict__ m1, const float* __restrict__ RSp,
    const float* __restrict__ g, const float* __restrict__ gamma_,
    const float* __restrict__ s,
    float* __restrict__ part, float* __restrict__ GSp)
{
  __shared__ float g_sh[64], gm_sh[64], ri_sh[64];
  __shared__ float s0_sh[64], s1_sh[64], s2_sh[64];
  __shared__ float w_shT[64 * 68];   // [n_local][b], pad 68
  __shared__ float gsred[4];
  const int sc = blockIdx.x, r = blockIdx.y;
  const int t = threadIdx.x;
  if (t < 64) {
    float rs = 0.f;
#pragma unroll
    for (int j = 0; j < 16; j++) rs += RSp[t * 256 + j * 16];
    ri_sh[t] = 1.0f / rs;
    g_sh[t] = g[t];
    gm_sh[t] = gamma_[t];
    s0_sh[t] = s[t * 3 + 0];
    s1_sh[t] = s[t * 3 + 1];
    s2_sh[t] = s[t * 3 + 2];
  }
  __syncthreads();
  const int n_l = t & 63, bg = t >> 6;
  const int bq = t >> 4, mq = t & 15;
  const float* __restrict__ wrr = wr + (size_t)r * BB * NN;
  float4 acc[4];
#pragma unroll
  for (int j = 0; j < 4; j++) acc[j] = make_float4(0.f, 0.f, 0.f, 0.f);
  float gs_acc = 0.f;

  for (int st = 0; st < 2; st++) {
    if (st) __syncthreads();  // gemm finished reading w_shT
    const int n0 = (sc * 2 + st) * 64;
    const int n = n0 + n_l;
    // ---- produce w tile: wave bg owns b in [bg*16, bg*16+16) ----
#pragma unroll
    for (int half = 0; half < 2; half++) {
      float ev[8], wv[8];
#pragma unroll
      for (int j = 0; j < 8; j++) {
        const int b = bg * 16 + half * 8 + j;
        ev[j] = E[(size_t)b * NN + n];
        wv[j] = wrr[(size_t)b * NN + n];
      }
#pragma unroll
      for (int j = 0; j < 8; j++) {
        const int b = bg * 16 + half * 8 + j;
        const float gri = g_sh[b] * ri_sh[b];
        const float omg = 1.f - g_sh[b];
        const float wgc = gri * ev[j] + omg * wv[j];
        float wgm = __shfl_up(wgc, 1, 64);
        float wgp = __shfl_down(wgc, 1, 64);
        if (n_l == 0)
          wgm = (n > 0) ? (gri * E[(size_t)b * NN + n - 1] + omg * wrr[(size_t)b * NN + n - 1]) : 0.f;
        if (n_l == 63)
          wgp = (n < NN - 1) ? (gri * E[(size_t)b * NN + n + 1] + omg * wrr[(size_t)b * NN + n + 1]) : 0.f;
        const float wt = s0_sh[b] * wgm + s1_sh[b] * wgc + s2_sh[b] * wgp;
        const float wp = fastPow(wt, gm_sh[b]);
        w_shT[n_l * 68 + b] = wp;
        gs_acc += wp;
      }
    }
    __syncthreads();
    // ---- gemm accumulate: thread (bq, mq): 4 b x 4 m; m1 from global/L2 ----
    const float4* __restrict__ m1p = (const float4*)(m1 + (size_t)n0 * MM);
#pragma unroll 4
    for (int nn = 0; nn < 64; nn++) {
      const float4 mv = m1p[nn * 16 + mq];
      const float4 wv4 = *((const float4*)&w_shT[nn * 68 + bq * 4]);
      acc[0].x += wv4.x * mv.x; acc[0].y += wv4.x * mv.y; acc[0].z += wv4.x * mv.z; acc[0].w += wv4.x * mv.w;
      acc[1].x += wv4.y * mv.x; acc[1].y += wv4.y * mv.y; acc[1].z += wv4.y * mv.z; acc[1].w += wv4.y * mv.w;
      acc[2].x += wv4.z * mv.x; acc[2].y += wv4.z * mv.y; acc[2].z += wv4.z * mv.z; acc[2].w += wv4.z * mv.w;
      acc[3].x += wv4.w * mv.x; acc[3].y += wv4.w * mv.y; acc[3].z += wv4.w * mv.z; acc[3].w += wv4.w * mv.w;
    }
  }
  float* pp = part + ((size_t)r * 512 + sc) * 4096;
#pragma unroll
  for (int j = 0; j < 4; j++)
    *((float4*)&pp[(bq * 4 + j) * 64 + mq * 4]) = acc[j];
  const float v = waveReduceSum(gs_acc);
  if (n_l == 0) gsred[bg] = v;
  __syncthreads();
  if (t == 0)
    atomicAdd(&GSp[(1 + r) * 1024 + (sc & 63) * 16],
              gsred[0] + gsred[1] + gsred[2] + gsred[3]);
}

// ---------------------------------------------------------------------------
// K7: reduce part[4][512][4096] + GS normalize. grid (64 b, 4 r), block 256.
// 4x the block parallelism of the 64-block version; float4-coalesced reads.
// ---------------------------------------------------------------------------
__global__ __launch_bounds__(256) void finalize_kernel(
    const float* __restrict__ part, const float* __restrict__ GSp,
    float* __restrict__ out)
{
  __shared__ float gs_sh;
  __shared__ float4 red[16][16];
  const int t = threadIdx.x;
  const int b = blockIdx.x, r = blockIdx.y;
  if (t < 64) {
    float v = GSp[(1 + r) * 1024 + t * 16];
    v = waveReduceSum(v);
    if (t == 0) gs_sh = v;
  }
  const int f = t & 15;       // float4 column within the 64-float m row
  const int chunk = t >> 4;   // 0..15, each sums 32 slabs
  const float4* p4 = (const float4*)part;
  const size_t base = (size_t)r * 512 * 1024 + (size_t)b * 16 + f;
  float4 sum = make_float4(0.f, 0.f, 0.f, 0.f);
#pragma unroll 8
  for (int k = chunk * 32; k < chunk * 32 + 32; k++) {
    const float4 v = p4[base + (size_t)k * 1024];
    sum.x += v.x; sum.y += v.y; sum.z += v.z; sum.w += v.w;
  }
  red[chunk][f] = sum;
  __syncthreads();
  if (t < 16) {
    float4 tot = make_float4(0.f, 0.f, 0.f, 0.f);
#pragma unroll
    for (int k = 0; k < 16; k++) {
      const float4 v = red[k][t];
      tot.x += v.x; tot.y += v.y; tot.z += v.z; tot.w += v.w;
    }
    const float inv = 1.0f / (gs_sh + 1e-5f);
    tot.x *= inv; tot.y *= inv; tot.z *= inv; tot.w *= inv;
    ((float4*)out)[b * 64 + r * 16 + t] = tot;
  }
}

// ---------------------------------------------------------------------------
extern "C" void kernel_launch(void* const* d_in, const int* in_sizes, int n_in,
                              void* d_out, int out_size, void* d_ws, size_t ws_size,
                              hipStream_t stream) {
  (void)in_sizes; (void)n_in; (void)out_size; (void)ws_size;
  const float* h_t    = (const float*)d_in[0];
  const float* ww     = (const float*)d_in[1];
  const float* wr     = (const float*)d_in[2];
  const float* memory = (const float*)d_in[3];
  const float* key_w  = (const float*)d_in[4];
  const float* key_b  = (const float*)d_in[5];
  const float* beta_w = (const float*)d_in[6];
  const float* beta_b = (const float*)d_in[7];
  const float* gate_w = (const float*)d_in[8];
  const float* gate_b = (const float*)d_in[9];
  const float* shift_w = (const float*)d_in[10];
  const float* shift_b = (const float*)d_in[11];
  const float* gamma_w = (const float*)d_in[12];
  const float* gamma_b = (const float*)d_in[13];
  const float* erase_w = (const float*)d_in[14];
  const float* erase_b = (const float*)d_in[15];
  const float* add_w   = (const float*)d_in[16];
  const float* add_b   = (const float*)d_in[17];
  const int*   bank    = (const int*)d_in[18];

  float* ws = (float*)d_ws;
  // slabs (floats): E0 @0, W0 @4M, m1 @8M, E1 @12M, smallb @16M,
  // part @20M (4 x 512 x 4096 = 8.39M floats = 33.6MB).
  float* E0   = ws;
  float* W0   = ws + 4194304;
  float* m1   = ws + 8388608;
  float* E1   = ws + 12582912;
  float* smallb = ws + 16777216;
  float* part = ws + 20971520;
  float* kn    = smallb;            // 4096
  float* e_v   = smallb + 4096;     // 4096
  float* a_v   = smallb + 8192;     // 4096
  float* betaB = smallb + 12288;    // 64
  float* g     = smallb + 12352;    // 64
  float* gam   = smallb + 12416;    // 64
  float* s     = smallb + 12480;    // 256 (192 used)
  float* RS0p  = smallb + 12800;    // 16384 (64 b x 16 slots x 16 pad)
  float* RS1p  = smallb + 29184;    // 16384
  float* GSp   = smallb + 45568;    // 5120 (5 slots x 64 x 16 pad)
  // RS0p/RS1p/GSp contiguous: zero range = smallb+12800 .. +50688

  prep_kernel<<<dim3(64, 4), 256, 0, stream>>>(
      h_t, key_w, key_b, erase_w, erase_b, add_w, add_b,
      beta_w, beta_b, gate_w, gate_b, shift_w, shift_b, gamma_w, gamma_b,
      kn, e_v, a_v, g, gam, s, betaB, smallb + 12800);
  content_kernel<<<dim3(1024, 2), 256, 0, stream>>>(memory, bank, kn, betaB, E0, RS0p);
  wpow_kernel<<<dim3(64, 64), 256, 0, stream>>>(E0, ww, RS0p, g, gam, s, W0, GSp, 0);
  apply_write_kernel<<<1024, 256, 0, stream>>>(W0, GSp, e_v, a_v, memory, bank, m1);
  content_kernel<<<dim3(1024, 2), 256, 0, stream>>>(m1, nullptr, kn, betaB, E1, RS1p);
  rheads_kernel<<<dim3(512, 4), 256, 0, stream>>>(E1, wr, m1, RS1p, g, gam, s, part, GSp);
  finalize_kernel<<<dim3(64, 4), 256, 0, stream>>>(part, GSp, (float*)d_out);
}